// Round 1
// baseline (1018.068 us; speedup 1.0000x reference)
//
#include <hip/hip_runtime.h>

#define BB 1024
#define TT 200
#define MROWS (BB*TT)   // 204800

typedef unsigned short u16;
typedef __attribute__((ext_vector_type(8))) short bf16x8;
typedef __attribute__((ext_vector_type(4))) float f32x4;

__device__ __forceinline__ u16 f2bf(float f) {
  unsigned u = __float_as_uint(f);
  u += 0x7fff + ((u >> 16) & 1);
  return (u16)(u >> 16);
}
__device__ __forceinline__ float bf2f(u16 h) {
  return __uint_as_float(((unsigned)h) << 16);
}

// ---------------------------------------------------------------------------
// K0: fold + transpose LAU weights to bf16.
// WpT[n][k] (256x256): k<128 -> W1[128+k][n]-W1[256+k][n] ; k>=128 -> W1[384+k-128][n]
// Wq [k][j] (128x256) fp32: W1[k][j]+W1[256+k][j]
// W2T[n][k] (128x256): W2[k][n]
// ---------------------------------------------------------------------------
__global__ void prep_weights(const float* __restrict__ w1, const float* __restrict__ w2,
                             u16* __restrict__ WpT, float* __restrict__ Wq,
                             u16* __restrict__ W2T) {
  int i = blockIdx.x * 256 + threadIdx.x;
  if (i < 65536) {
    int n = i >> 8, k = i & 255;
    float v;
    if (k < 128) v = w1[(128 + k) * 256 + n] - w1[(256 + k) * 256 + n];
    else         v = w1[(384 + (k - 128)) * 256 + n];
    WpT[n * 256 + k] = f2bf(v);
  } else if (i < 98304) {
    int j = i - 65536;           // j = k*256 + jc
    int k = j >> 8, jc = j & 255;
    Wq[j] = w1[k * 256 + jc] + w1[(256 + k) * 256 + jc];
  } else if (i < 131072) {
    int j = i - 98304;           // j = n*256 + k
    int n = j >> 8, k = j & 255;
    W2T[j] = f2bf(w2[k * 128 + n]);
  }
}

// ---------------------------------------------------------------------------
// K1: per-batch cur gather + bias1p = lau_b1 + cur @ Wq  (fp32)
// ---------------------------------------------------------------------------
__global__ __launch_bounds__(256) void prep_batch(
    const int* __restrict__ mid, const int* __restrict__ cat,
    const float* __restrict__ mat_table, const float* __restrict__ cat_table,
    const float* __restrict__ lau_b1, const float* __restrict__ Wq,
    float* __restrict__ cur, float* __restrict__ bias1p) {
  int b = blockIdx.x, tid = threadIdx.x;
  __shared__ float curL[128];
  if (tid < 64)        curL[tid] = mat_table[(long)mid[b] * 64 + tid];
  else if (tid < 128)  curL[tid] = cat_table[(long)cat[b] * 64 + (tid - 64)];
  __syncthreads();
  if (tid < 128) cur[b * 128 + tid] = curL[tid];
  float s = lau_b1[tid];
  for (int k = 0; k < 128; ++k) s += curL[k] * Wq[k * 256 + tid];
  bias1p[b * 256 + tid] = s;
}

// ---------------------------------------------------------------------------
// K2: gather hist, build X = [hist(128) | cur*hist(128)] bf16 per (b,t) row
// grid: B*T*128/256 blocks
// ---------------------------------------------------------------------------
__global__ void gather_hist(const int* __restrict__ hmid, const int* __restrict__ hcat,
                            const float* __restrict__ mat_table,
                            const float* __restrict__ cat_table,
                            const float* __restrict__ cur, u16* __restrict__ X) {
  int idx = blockIdx.x * 256 + threadIdx.x;   // < B*T*128
  int bt = idx >> 7, e = idx & 127;
  int b = bt / TT;
  float hv;
  if (e < 64) hv = mat_table[(long)hmid[bt] * 64 + e];
  else        hv = cat_table[(long)hcat[bt] * 64 + (e - 64)];
  long base = (long)bt * 256;
  X[base + e]       = f2bf(hv);
  X[base + 128 + e] = f2bf(hv * cur[b * 128 + e]);
}

// ---------------------------------------------------------------------------
// K3: LAU layer1 GEMM: h1 = sigmoid(X[M,256] @ Wp[256,256] + bias1p[b]) -> bf16
// block: 256 thr (4 waves). Block tile 64 x 256 (wave w covers n in [64w,64w+64)).
// ---------------------------------------------------------------------------
__global__ __launch_bounds__(256) void lau_gemm1(
    const u16* __restrict__ X, const u16* __restrict__ WpT,
    const float* __restrict__ bias1p, u16* __restrict__ H1) {
  __shared__ __align__(16) u16 Al[64 * 264];   // rows padded +8 bf16
  __shared__ __align__(16) u16 Bl[256 * 40];   // 32-k slice, padded +8
  int tid = threadIdx.x, wave = tid >> 6, l = tid & 63;
  long mBase = (long)blockIdx.x * 64;

  for (int i = tid; i < 2048; i += 256) {      // stage A: 64 rows x 32 chunks(16B)
    int r = i >> 5, c = i & 31;
    uint4 v = *(const uint4*)(X + (mBase + r) * 256 + c * 8);
    *(uint4*)(Al + r * 264 + c * 8) = v;
  }
  f32x4 acc[4][4] = {};
  int q = l >> 4, r16 = l & 15;
  for (int ki = 0; ki < 8; ++ki) {
    __syncthreads();
    for (int i = tid; i < 1024; i += 256) {    // stage B slice: 256 rows x 4 chunks
      int n = i >> 2, c = i & 3;
      uint4 v = *(const uint4*)(WpT + n * 256 + ki * 32 + c * 8);
      *(uint4*)(Bl + n * 40 + c * 8) = v;
    }
    __syncthreads();
    bf16x8 a[4], bq[4];
    for (int mt = 0; mt < 4; ++mt)
      a[mt] = *(const bf16x8*)(Al + (mt * 16 + r16) * 264 + ki * 32 + q * 8);
    for (int nt = 0; nt < 4; ++nt)
      bq[nt] = *(const bf16x8*)(Bl + (wave * 64 + nt * 16 + r16) * 40 + q * 8);
    for (int mt = 0; mt < 4; ++mt)
      for (int nt = 0; nt < 4; ++nt)
        acc[mt][nt] = __builtin_amdgcn_mfma_f32_16x16x32_bf16(a[mt], bq[nt], acc[mt][nt], 0, 0, 0);
  }
  for (int mt = 0; mt < 4; ++mt)
    for (int r = 0; r < 4; ++r) {
      long gm = mBase + mt * 16 + q * 4 + r;
      int bidx = (int)(gm / TT);
      for (int nt = 0; nt < 4; ++nt) {
        int gn = wave * 64 + nt * 16 + r16;
        float z = acc[mt][nt][r] + bias1p[bidx * 256 + gn];
        float s = 1.f / (1.f + __expf(-z));
        H1[gm * 256 + gn] = f2bf(s);
      }
    }
}

// ---------------------------------------------------------------------------
// K4: LAU layer2+3: h2 = sigmoid(h1 @ W2 + b2); aw = h2 @ w3 + b3
// block tile 64 x 128 (wave w covers n in [32w, 32w+32))
// ---------------------------------------------------------------------------
__global__ __launch_bounds__(256) void lau_gemm23(
    const u16* __restrict__ H1, const u16* __restrict__ W2T,
    const float* __restrict__ b2, const float* __restrict__ w3,
    const float* __restrict__ b3, float* __restrict__ AW) {
  __shared__ __align__(16) u16 Al[64 * 264];
  __shared__ __align__(16) u16 Bl[128 * 40];
  __shared__ float H2[64 * 129];
  int tid = threadIdx.x, wave = tid >> 6, l = tid & 63;
  long mBase = (long)blockIdx.x * 64;

  for (int i = tid; i < 2048; i += 256) {
    int r = i >> 5, c = i & 31;
    uint4 v = *(const uint4*)(H1 + (mBase + r) * 256 + c * 8);
    *(uint4*)(Al + r * 264 + c * 8) = v;
  }
  f32x4 acc[4][2] = {};
  int q = l >> 4, r16 = l & 15;
  for (int ki = 0; ki < 8; ++ki) {
    __syncthreads();
    for (int i = tid; i < 512; i += 256) {     // 128 rows x 4 chunks
      int n = i >> 2, c = i & 3;
      uint4 v = *(const uint4*)(W2T + n * 256 + ki * 32 + c * 8);
      *(uint4*)(Bl + n * 40 + c * 8) = v;
    }
    __syncthreads();
    bf16x8 a[4], bq[2];
    for (int mt = 0; mt < 4; ++mt)
      a[mt] = *(const bf16x8*)(Al + (mt * 16 + r16) * 264 + ki * 32 + q * 8);
    for (int nt = 0; nt < 2; ++nt)
      bq[nt] = *(const bf16x8*)(Bl + (wave * 32 + nt * 16 + r16) * 40 + q * 8);
    for (int mt = 0; mt < 4; ++mt)
      for (int nt = 0; nt < 2; ++nt)
        acc[mt][nt] = __builtin_amdgcn_mfma_f32_16x16x32_bf16(a[mt], bq[nt], acc[mt][nt], 0, 0, 0);
  }
  for (int mt = 0; mt < 4; ++mt)
    for (int r = 0; r < 4; ++r) {
      int row = mt * 16 + q * 4 + r;
      for (int nt = 0; nt < 2; ++nt) {
        int col = wave * 32 + nt * 16 + r16;
        float z = acc[mt][nt][r] + b2[col];
        H2[row * 129 + col] = 1.f / (1.f + __expf(-z));
      }
    }
  __syncthreads();
  if (tid < 64) {
    float s = b3[0];
    for (int k = 0; k < 128; ++k) s += H2[tid * 129 + k] * w3[k];
    AW[mBase + tid] = s;
  }
}

// ---------------------------------------------------------------------------
// K5: per-b masked softmax over T, weighted pools, assemble x[B,448]
// x = [u(64) | cur(128) | lau(128) | hmean(128)]
// ---------------------------------------------------------------------------
__global__ __launch_bounds__(256) void softmax_pool(
    const float* __restrict__ AW, const int* __restrict__ mask,
    const int* __restrict__ uid, const float* __restrict__ user_table,
    const float* __restrict__ cur, const u16* __restrict__ X,
    float* __restrict__ Xmlp) {
  int b = blockIdx.x, tid = threadIdx.x;
  __shared__ float red[256];
  __shared__ float sc[TT];
  __shared__ float mkf[TT];
  int mk = 0;
  float masked = -3.0e38f;
  if (tid < TT) {
    mk = mask[b * TT + tid];
    float a = AW[b * TT + tid];
    masked = mk ? a : -2147483648.0f;
  }
  red[tid] = masked; __syncthreads();
  for (int s = 128; s > 0; s >>= 1) { if (tid < s) red[tid] = fmaxf(red[tid], red[tid + s]); __syncthreads(); }
  float mx = red[0]; __syncthreads();
  float ev = (tid < TT) ? __expf(masked - mx) : 0.f;
  red[tid] = ev; __syncthreads();
  for (int s = 128; s > 0; s >>= 1) { if (tid < s) red[tid] += red[tid + s]; __syncthreads(); }
  float denom = red[0]; __syncthreads();
  red[tid] = (tid < TT) ? (float)mk : 0.f; __syncthreads();
  for (int s = 128; s > 0; s >>= 1) { if (tid < s) red[tid] += red[tid + s]; __syncthreads(); }
  float cnt = red[0]; __syncthreads();
  if (tid < TT) { sc[tid] = (ev / denom) * (float)mk; mkf[tid] = (float)mk; }
  __syncthreads();
  if (tid < 128) {
    float sL = 0.f, sH = 0.f;
    for (int t = 0; t < TT; ++t) {
      float hv = bf2f(X[((long)b * TT + t) * 256 + tid]);
      sL += sc[t] * hv;
      sH += mkf[t] * hv;
    }
    Xmlp[b * 448 + 192 + tid] = sL;
    Xmlp[b * 448 + 320 + tid] = sH / cnt;
  } else {
    int j = tid - 128;
    Xmlp[b * 448 + 64 + j] = cur[b * 128 + j];
    if (j < 64) Xmlp[b * 448 + j] = user_table[(long)uid[b] * 64 + j];
  }
}

// ---------------------------------------------------------------------------
// BN stats: per-column mean/var over 1024 rows -> scale/shift (folds gamma/beta)
// grid: cols/64 blocks x 256 thr
// ---------------------------------------------------------------------------
__global__ __launch_bounds__(256) void bn_stats(const float* __restrict__ Xin, int cols,
                                                const float* __restrict__ g,
                                                const float* __restrict__ bta,
                                                float* __restrict__ scale,
                                                float* __restrict__ shift) {
  __shared__ float s1[256], s2[256];
  int col = blockIdx.x * 64 + (threadIdx.x & 63);
  int rq = threadIdx.x >> 6;
  float a = 0.f, bsum = 0.f;
  for (int r = rq; r < BB; r += 4) {
    float v = Xin[(long)r * cols + col];
    a += v; bsum += v * v;
  }
  s1[threadIdx.x] = a; s2[threadIdx.x] = bsum;
  __syncthreads();
  if (threadIdx.x < 64) {
    a    = s1[threadIdx.x] + s1[threadIdx.x + 64] + s1[threadIdx.x + 128] + s1[threadIdx.x + 192];
    bsum = s2[threadIdx.x] + s2[threadIdx.x + 64] + s2[threadIdx.x + 128] + s2[threadIdx.x + 192];
    float mu = a * (1.f / 1024.f);
    float var = bsum * (1.f / 1024.f) - mu * mu;
    float rs = rsqrtf(var + 1e-5f);
    float scv = rs * g[col];
    scale[col] = scv;
    shift[col] = bta[col] - mu * scv;
  }
}

template <bool LEAKY>
__global__ void bn_apply(const float* __restrict__ Xin, const float* __restrict__ scale,
                         const float* __restrict__ shift, float* __restrict__ Xout,
                         int n, int cols) {
  int i = blockIdx.x * 256 + threadIdx.x;
  if (i >= n) return;
  int c = i % cols;
  float v = Xin[i] * scale[c] + shift[c];
  if (LEAKY) v = v > 0.f ? v : 0.1f * v;
  Xout[i] = v;
}

// ---------------------------------------------------------------------------
// fp32 SGEMM: C[M,N] = A[M,K] @ B[K,N] + bias[n]. 64x64 tile, BK=16, 4x4/thr.
// ---------------------------------------------------------------------------
__global__ __launch_bounds__(256) void sgemm_bias(const float* __restrict__ A,
                                                  const float* __restrict__ Bm,
                                                  const float* __restrict__ bias,
                                                  float* __restrict__ C,
                                                  int M, int N, int K) {
  __shared__ float As[16][65];
  __shared__ float Bs[16][65];
  int tid = threadIdx.x;
  int m0 = blockIdx.x * 64, n0 = blockIdx.y * 64;
  int tx = tid & 15, ty = tid >> 4;
  float acc[4][4] = {};
  for (int k0 = 0; k0 < K; k0 += 16) {
    __syncthreads();
    for (int i = tid; i < 1024; i += 256) {
      int m = i >> 4, k = i & 15;
      As[k][m] = A[(long)(m0 + m) * K + k0 + k];
    }
    for (int i = tid; i < 1024; i += 256) {
      int k = i >> 6, n = i & 63;
      Bs[k][n] = Bm[(long)(k0 + k) * N + n0 + n];
    }
    __syncthreads();
    for (int k = 0; k < 16; ++k) {
      float a[4], bq[4];
      for (int ii = 0; ii < 4; ++ii) a[ii]  = As[k][ty * 4 + ii];
      for (int jj = 0; jj < 4; ++jj) bq[jj] = Bs[k][tx * 4 + jj];
      for (int ii = 0; ii < 4; ++ii)
        for (int jj = 0; jj < 4; ++jj) acc[ii][jj] += a[ii] * bq[jj];
    }
  }
  for (int ii = 0; ii < 4; ++ii)
    for (int jj = 0; jj < 4; ++jj) {
      int m = m0 + ty * 4 + ii, n = n0 + tx * 4 + jj;
      C[(long)m * N + n] = acc[ii][jj] + bias[n];
    }
}

// ---------------------------------------------------------------------------
// Final: out = leaky(bn2(y2)) @ W3[256,2] + b3
// ---------------------------------------------------------------------------
__global__ void final_mlp3(const float* __restrict__ y2, const float* __restrict__ scale2,
                           const float* __restrict__ shift2, const float* __restrict__ w3,
                           const float* __restrict__ b3, float* __restrict__ out) {
  int r = blockIdx.x * blockDim.x + threadIdx.x;
  if (r >= BB) return;
  float a0 = 0.f, a1 = 0.f;
  for (int k = 0; k < 256; ++k) {
    float v = y2[r * 256 + k] * scale2[k] + shift2[k];
    v = v > 0.f ? v : 0.1f * v;
    a0 += v * w3[k * 2 + 0];
    a1 += v * w3[k * 2 + 1];
  }
  out[r * 2 + 0] = a0 + b3[0];
  out[r * 2 + 1] = a1 + b3[1];
}

// ---------------------------------------------------------------------------

extern "C" void kernel_launch(void* const* d_in, const int* in_sizes, int n_in,
                              void* d_out, int out_size, void* d_ws, size_t ws_size,
                              hipStream_t stream) {
  const int* uid  = (const int*)d_in[0];
  const int* mid  = (const int*)d_in[1];
  const int* cat  = (const int*)d_in[2];
  const int* hmid = (const int*)d_in[3];
  const int* hcat = (const int*)d_in[4];
  const int* mask = (const int*)d_in[5];
  const float* user_table = (const float*)d_in[6];
  const float* mat_table  = (const float*)d_in[7];
  const float* cat_table  = (const float*)d_in[8];
  const float* lau_w1 = (const float*)d_in[9];
  const float* lau_b1 = (const float*)d_in[10];
  const float* lau_w2 = (const float*)d_in[11];
  const float* lau_b2 = (const float*)d_in[12];
  const float* lau_w3 = (const float*)d_in[13];
  const float* lau_b3 = (const float*)d_in[14];
  const float* bn0_g = (const float*)d_in[15];
  const float* bn0_b = (const float*)d_in[16];
  const float* mlp_w1 = (const float*)d_in[17];
  const float* mlp_b1 = (const float*)d_in[18];
  const float* bn1_g = (const float*)d_in[19];
  const float* bn1_b = (const float*)d_in[20];
  const float* mlp_w2 = (const float*)d_in[21];
  const float* mlp_b2 = (const float*)d_in[22];
  const float* bn2_g = (const float*)d_in[23];
  const float* bn2_b = (const float*)d_in[24];
  const float* mlp_w3 = (const float*)d_in[25];
  const float* mlp_b3 = (const float*)d_in[26];
  float* out = (float*)d_out;

  char* w = (char*)d_ws;
  size_t off = 0;
  auto take = [&](size_t bytes) { size_t o = off; off += (bytes + 255) & ~(size_t)255; return o; };
  u16*   X      = (u16*)  (w + take((size_t)MROWS * 256 * 2));
  u16*   H1     = (u16*)  (w + take((size_t)MROWS * 256 * 2));
  float* AW     = (float*)(w + take((size_t)MROWS * 4));
  float* cur    = (float*)(w + take((size_t)BB * 128 * 4));
  float* bias1p = (float*)(w + take((size_t)BB * 256 * 4));
  float* xmlp   = (float*)(w + take((size_t)BB * 448 * 4));
  float* xn     = (float*)(w + take((size_t)BB * 448 * 4));
  float* y1     = (float*)(w + take((size_t)BB * 512 * 4));
  float* a1     = (float*)(w + take((size_t)BB * 512 * 4));
  float* y2     = (float*)(w + take((size_t)BB * 256 * 4));
  u16*   WpT    = (u16*)  (w + take(256 * 256 * 2));
  float* Wq     = (float*)(w + take(128 * 256 * 4));
  u16*   W2T    = (u16*)  (w + take(128 * 256 * 2));
  float* scale0 = (float*)(w + take(448 * 4));
  float* shift0 = (float*)(w + take(448 * 4));
  float* scale1 = (float*)(w + take(512 * 4));
  float* shift1 = (float*)(w + take(512 * 4));
  float* scale2 = (float*)(w + take(256 * 4));
  float* shift2 = (float*)(w + take(256 * 4));

  prep_weights<<<512, 256, 0, stream>>>(lau_w1, lau_w2, WpT, Wq, W2T);
  prep_batch<<<BB, 256, 0, stream>>>(mid, cat, mat_table, cat_table, lau_b1, Wq, cur, bias1p);
  gather_hist<<<(BB * TT * 128) / 256, 256, 0, stream>>>(hmid, hcat, mat_table, cat_table, cur, X);
  lau_gemm1<<<MROWS / 64, 256, 0, stream>>>(X, WpT, bias1p, H1);
  lau_gemm23<<<MROWS / 64, 256, 0, stream>>>(H1, W2T, lau_b2, lau_w3, lau_b3, AW);
  softmax_pool<<<BB, 256, 0, stream>>>(AW, mask, uid, user_table, cur, X, xmlp);

  bn_stats<<<448 / 64, 256, 0, stream>>>(xmlp, 448, bn0_g, bn0_b, scale0, shift0);
  bn_apply<false><<<(BB * 448 + 255) / 256, 256, 0, stream>>>(xmlp, scale0, shift0, xn, BB * 448, 448);
  {
    dim3 g(1024 / 64, 512 / 64);
    sgemm_bias<<<g, 256, 0, stream>>>(xn, mlp_w1, mlp_b1, y1, 1024, 512, 448);
  }
  bn_stats<<<512 / 64, 256, 0, stream>>>(y1, 512, bn1_g, bn1_b, scale1, shift1);
  bn_apply<true><<<(BB * 512 + 255) / 256, 256, 0, stream>>>(y1, scale1, shift1, a1, BB * 512, 512);
  {
    dim3 g(1024 / 64, 256 / 64);
    sgemm_bias<<<g, 256, 0, stream>>>(a1, mlp_w2, mlp_b2, y2, 1024, 256, 512);
  }
  bn_stats<<<256 / 64, 256, 0, stream>>>(y2, 256, bn2_g, bn2_b, scale2, shift2);
  final_mlp3<<<BB / 256, 256, 0, stream>>>(y2, scale2, shift2, mlp_w3, mlp_b3, out);
}

// Round 2
// 779.886 us; speedup vs baseline: 1.3054x; 1.3054x over previous
//
#include <hip/hip_runtime.h>

#define BB 1024
#define TT 200
#define MROWS (BB*TT)   // 204800

typedef unsigned short u16;
typedef __attribute__((ext_vector_type(8))) short bf16x8;
typedef __attribute__((ext_vector_type(4))) float f32x4;

__device__ __forceinline__ u16 f2bf(float f) {
  unsigned u = __float_as_uint(f);
  u += 0x7fff + ((u >> 16) & 1);
  return (u16)(u >> 16);
}
__device__ __forceinline__ float bf2f(u16 h) {
  return __uint_as_float(((unsigned)h) << 16);
}

// ---------------------------------------------------------------------------
// K0: fold + transpose LAU weights to bf16.
// comb = [cur, hist, cur-hist, cur*hist] @ W1  ==  cur@(Wa+Wc) + hist@(Wb-Wc) + (cur*hist)@Wd
// WpT[n][k] (256x256): k<128 -> W1[128+k][n]-W1[256+k][n] ; k>=128 -> W1[384+k-128][n]
// Wq [k][j] (128x256) fp32: W1[k][j]+W1[256+k][j]
// W2T[n][k] (128x256): W2[k][n]
// ---------------------------------------------------------------------------
__global__ void prep_weights(const float* __restrict__ w1, const float* __restrict__ w2,
                             u16* __restrict__ WpT, float* __restrict__ Wq,
                             u16* __restrict__ W2T) {
  int i = blockIdx.x * 256 + threadIdx.x;
  if (i < 65536) {
    int n = i >> 8, k = i & 255;
    float v;
    if (k < 128) v = w1[(128 + k) * 256 + n] - w1[(256 + k) * 256 + n];
    else         v = w1[(384 + (k - 128)) * 256 + n];
    WpT[n * 256 + k] = f2bf(v);
  } else if (i < 98304) {
    int j = i - 65536;
    int k = j >> 8, jc = j & 255;
    Wq[j] = w1[k * 256 + jc] + w1[(256 + k) * 256 + jc];
  } else if (i < 131072) {
    int j = i - 98304;           // j = n*256 + k
    int n = j >> 8, k = j & 255;
    W2T[j] = f2bf(w2[k * 128 + n]);
  }
}

// ---------------------------------------------------------------------------
// K1: per-batch cur gather + bias1p = lau_b1 + cur @ Wq  (fp32)
// ---------------------------------------------------------------------------
__global__ __launch_bounds__(256) void prep_batch(
    const int* __restrict__ mid, const int* __restrict__ cat,
    const float* __restrict__ mat_table, const float* __restrict__ cat_table,
    const float* __restrict__ lau_b1, const float* __restrict__ Wq,
    float* __restrict__ cur, float* __restrict__ bias1p) {
  int b = blockIdx.x, tid = threadIdx.x;
  __shared__ float curL[128];
  if (tid < 64)        curL[tid] = mat_table[(long)mid[b] * 64 + tid];
  else if (tid < 128)  curL[tid] = cat_table[(long)cat[b] * 64 + (tid - 64)];
  __syncthreads();
  if (tid < 128) cur[b * 128 + tid] = curL[tid];
  float s = lau_b1[tid];
  for (int k = 0; k < 128; ++k) s += curL[k] * Wq[k * 256 + tid];
  bias1p[b * 256 + tid] = s;
}

// ---------------------------------------------------------------------------
// K2 (fused): gather hist -> LDS comb -> gemm1 -> sigmoid(h1) in-place ->
//             gemm2 -> sigmoid(h2) -> dot w3 -> AW.  Also writes Xh (hist bf16).
// 64 rows per block, 4 waves; wave w owns cols [64w,64w+64) (L1) / [32w,32w+32) (L2).
// ---------------------------------------------------------------------------
__global__ __launch_bounds__(256) void lau_fused(
    const int* __restrict__ hmid, const int* __restrict__ hcat,
    const float* __restrict__ mat_table, const float* __restrict__ cat_table,
    const float* __restrict__ cur, const float* __restrict__ bias1p,
    const u16* __restrict__ WpT, const u16* __restrict__ W2T,
    const float* __restrict__ b2, const float* __restrict__ w3,
    const float* __restrict__ b3,
    u16* __restrict__ Xh, float* __restrict__ AW) {
  __shared__ __align__(16) u16 Al[64 * 264];   // comb rows (later h1), +8 pad
  __shared__ __align__(16) u16 Bl[256 * 40];   // 32-k weight slice, +8 pad
  __shared__ float awp[4][64];
  int tid = threadIdx.x, wave = tid >> 6, l = tid & 63;
  int q = l >> 4, r16 = l & 15;
  long mBase = (long)blockIdx.x * 64;

  // gather: 64 rows x 128 fp32 (mat 0-63, cat 64-127); build [hist | cur*hist] bf16
  for (int i = tid; i < 2048; i += 256) {
    int r = i >> 5, c4 = i & 31;
    long bt = mBase + r;
    int b = (int)(bt / TT);
    int e0 = c4 * 4;
    float4 hv;
    if (e0 < 64) hv = *(const float4*)(mat_table + (long)hmid[bt] * 64 + e0);
    else         hv = *(const float4*)(cat_table + (long)hcat[bt] * 64 + (e0 - 64));
    float4 cv = *(const float4*)(cur + b * 128 + e0);
    u16 hb[4] = {f2bf(hv.x), f2bf(hv.y), f2bf(hv.z), f2bf(hv.w)};
    u16 pb[4] = {f2bf(hv.x * cv.x), f2bf(hv.y * cv.y), f2bf(hv.z * cv.z), f2bf(hv.w * cv.w)};
    *(ushort4*)(Al + r * 264 + e0)       = *(ushort4*)hb;
    *(ushort4*)(Al + r * 264 + 128 + e0) = *(ushort4*)pb;
    *(ushort4*)(Xh + bt * 128 + e0)      = *(ushort4*)hb;
  }

  // ---- layer 1: h1 = sigmoid(comb @ Wp + bias1p) ----
  f32x4 acc1[4][4] = {};
  for (int ki = 0; ki < 8; ++ki) {
    __syncthreads();
    for (int i = tid; i < 1024; i += 256) {
      int n = i >> 2, c = i & 3;
      *(uint4*)(Bl + n * 40 + c * 8) = *(const uint4*)(WpT + n * 256 + ki * 32 + c * 8);
    }
    __syncthreads();
    bf16x8 a[4], bq[4];
    for (int mt = 0; mt < 4; ++mt)
      a[mt] = *(const bf16x8*)(Al + (mt * 16 + r16) * 264 + ki * 32 + q * 8);
    for (int nt = 0; nt < 4; ++nt)
      bq[nt] = *(const bf16x8*)(Bl + (wave * 64 + nt * 16 + r16) * 40 + q * 8);
    for (int mt = 0; mt < 4; ++mt)
      for (int nt = 0; nt < 4; ++nt)
        acc1[mt][nt] = __builtin_amdgcn_mfma_f32_16x16x32_bf16(a[mt], bq[nt], acc1[mt][nt], 0, 0, 0);
  }
  __syncthreads();   // all Al reads done before overwrite
  for (int mt = 0; mt < 4; ++mt)
    for (int r = 0; r < 4; ++r) {
      int row = mt * 16 + q * 4 + r;
      int bidx = (int)((mBase + row) / TT);
      const float* bp = bias1p + (long)bidx * 256;
      for (int nt = 0; nt < 4; ++nt) {
        int col = wave * 64 + nt * 16 + r16;
        float z = acc1[mt][nt][r] + bp[col];
        Al[row * 264 + col] = f2bf(1.f / (1.f + __expf(-z)));
      }
    }
  __syncthreads();

  // ---- layer 2: h2 = sigmoid(h1 @ W2 + b2); aw = h2 @ w3 + b3 ----
  f32x4 acc2[4][2] = {};
  for (int ki = 0; ki < 8; ++ki) {
    __syncthreads();
    for (int i = tid; i < 512; i += 256) {
      int n = i >> 2, c = i & 3;
      *(uint4*)(Bl + n * 40 + c * 8) = *(const uint4*)(W2T + n * 256 + ki * 32 + c * 8);
    }
    __syncthreads();
    bf16x8 a[4], bq[2];
    for (int mt = 0; mt < 4; ++mt)
      a[mt] = *(const bf16x8*)(Al + (mt * 16 + r16) * 264 + ki * 32 + q * 8);
    for (int nt = 0; nt < 2; ++nt)
      bq[nt] = *(const bf16x8*)(Bl + (wave * 32 + nt * 16 + r16) * 40 + q * 8);
    for (int mt = 0; mt < 4; ++mt)
      for (int nt = 0; nt < 2; ++nt)
        acc2[mt][nt] = __builtin_amdgcn_mfma_f32_16x16x32_bf16(a[mt], bq[nt], acc2[mt][nt], 0, 0, 0);
  }
  float rp[4][4];
  for (int mt = 0; mt < 4; ++mt)
    for (int r = 0; r < 4; ++r) rp[mt][r] = 0.f;
  for (int nt = 0; nt < 2; ++nt) {
    int col = wave * 32 + nt * 16 + r16;
    float b2v = b2[col], w3v = w3[col];
    for (int mt = 0; mt < 4; ++mt)
      for (int r = 0; r < 4; ++r) {
        float z = acc2[mt][nt][r] + b2v;
        rp[mt][r] += w3v / (1.f + __expf(-z));
      }
  }
  for (int off = 1; off < 16; off <<= 1)
    for (int mt = 0; mt < 4; ++mt)
      for (int r = 0; r < 4; ++r)
        rp[mt][r] += __shfl_xor(rp[mt][r], off, 16);
  if (r16 == 0)
    for (int mt = 0; mt < 4; ++mt)
      for (int r = 0; r < 4; ++r)
        awp[wave][mt * 16 + q * 4 + r] = rp[mt][r];
  __syncthreads();
  if (tid < 64)
    AW[mBase + tid] = awp[0][tid] + awp[1][tid] + awp[2][tid] + awp[3][tid] + b3[0];
}

// ---------------------------------------------------------------------------
// K3: per-b masked softmax over T, weighted pools from Xh, assemble x[B,448]
// ---------------------------------------------------------------------------
__global__ __launch_bounds__(256) void softmax_pool(
    const float* __restrict__ AW, const int* __restrict__ mask,
    const int* __restrict__ uid, const float* __restrict__ user_table,
    const float* __restrict__ cur, const u16* __restrict__ Xh,
    float* __restrict__ Xmlp) {
  int b = blockIdx.x, tid = threadIdx.x;
  __shared__ float red[256];
  __shared__ float sc[TT], mkf[TT];
  __shared__ float ps[512];
  int mk = 0;
  float masked = -3.0e38f;
  if (tid < TT) {
    mk = mask[b * TT + tid];
    masked = mk ? AW[b * TT + tid] : -2147483648.0f;
  }
  red[tid] = masked; __syncthreads();
  for (int s = 128; s > 0; s >>= 1) { if (tid < s) red[tid] = fmaxf(red[tid], red[tid + s]); __syncthreads(); }
  float mx = red[0]; __syncthreads();
  float ev = (tid < TT) ? __expf(masked - mx) : 0.f;
  red[tid] = ev; __syncthreads();
  for (int s = 128; s > 0; s >>= 1) { if (tid < s) red[tid] += red[tid + s]; __syncthreads(); }
  float denom = red[0]; __syncthreads();
  red[tid] = (tid < TT) ? (float)mk : 0.f; __syncthreads();
  for (int s = 128; s > 0; s >>= 1) { if (tid < s) red[tid] += red[tid + s]; __syncthreads(); }
  float cnt = red[0]; __syncthreads();
  if (tid < TT) { sc[tid] = (ev / denom) * (float)mk; mkf[tid] = (float)mk; }
  __syncthreads();
  int c = tid & 127, p = tid >> 7;
  const u16* xb = Xh + (long)b * TT * 128 + c;
  float sL = 0.f, sH = 0.f;
  for (int t = p; t < TT; t += 2) {
    float hv = bf2f(xb[(long)t * 128]);
    sL += sc[t] * hv;
    sH += mkf[t] * hv;
  }
  ps[tid] = sL; ps[256 + tid] = sH;
  __syncthreads();
  if (tid < 128) {
    float lau  = ps[tid] + ps[tid + 128];
    float hsum = ps[256 + tid] + ps[256 + tid + 128];
    Xmlp[b * 448 + 192 + tid] = lau;
    Xmlp[b * 448 + 320 + tid] = hsum / cnt;
  } else {
    int j = tid - 128;
    Xmlp[b * 448 + 64 + j] = cur[b * 128 + j];
    if (j < 64) Xmlp[b * 448 + j] = user_table[(long)uid[b] * 64 + j];
  }
}

// ---------------------------------------------------------------------------
// K4: column partial sums/sumsq of X[1024, cols] into [16][cols] chunks
// grid: (cols/64, 16)
// ---------------------------------------------------------------------------
__global__ __launch_bounds__(256) void colstats(const float* __restrict__ X, int cols,
                                                float* __restrict__ psum,
                                                float* __restrict__ psq) {
  int cg = blockIdx.x, rc = blockIdx.y;
  int c = threadIdx.x & 63, ty = threadIdx.x >> 6;
  int col = cg * 64 + c;
  float s = 0.f, ss = 0.f;
  for (int i = 0; i < 16; ++i) {
    int r = rc * 64 + ty + i * 4;
    float v = X[(long)r * cols + col];
    s += v; ss += v * v;
  }
  __shared__ float s1[256], s2[256];
  s1[threadIdx.x] = s; s2[threadIdx.x] = ss;
  __syncthreads();
  if (ty == 0) {
    s  = s1[c] + s1[c + 64] + s1[c + 128] + s1[c + 192];
    ss = s2[c] + s2[c + 64] + s2[c + 128] + s2[c + 192];
    psum[rc * cols + col] = s;
    psq [rc * cols + col] = ss;
  }
}

// ---------------------------------------------------------------------------
// K5: C[1024,N] = (act(bn(A)) @ W) + bias, and per-M-tile column stats of C.
// bn scale/shift reconstructed from partials in LDS. 64x64 tiles, BK=16.
// ---------------------------------------------------------------------------
template <bool LEAKY>
__global__ __launch_bounds__(256) void gemm_bn(
    const float* __restrict__ A, int K,
    const float* __restrict__ psumA, const float* __restrict__ psqA,
    const float* __restrict__ g, const float* __restrict__ bta,
    const float* __restrict__ W, const float* __restrict__ bias, int N,
    float* __restrict__ C, float* __restrict__ psumC, float* __restrict__ psqC) {
  __shared__ float As[16][65], Bs[16][65];
  __shared__ float scK[512], shK[512];
  __shared__ float colS[16][64], colQ[16][64];
  int tid = threadIdx.x;
  for (int j = tid; j < K; j += 256) {
    float s = 0.f, ss = 0.f;
    for (int rc = 0; rc < 16; ++rc) { s += psumA[rc * K + j]; ss += psqA[rc * K + j]; }
    float mu = s * (1.f / 1024.f), var = ss * (1.f / 1024.f) - mu * mu;
    float scv = rsqrtf(var + 1e-5f) * g[j];
    scK[j] = scv; shK[j] = bta[j] - mu * scv;
  }
  __syncthreads();
  int m0 = blockIdx.x * 64, n0 = blockIdx.y * 64;
  int tx = tid & 15, ty = tid >> 4;
  float acc[4][4] = {};
  for (int k0 = 0; k0 < K; k0 += 16) {
    __syncthreads();
    for (int i = tid; i < 1024; i += 256) {
      int m = i >> 4, k = i & 15;
      float v = A[(long)(m0 + m) * K + k0 + k] * scK[k0 + k] + shK[k0 + k];
      if (LEAKY) v = v > 0.f ? v : 0.1f * v;
      As[k][m] = v;
    }
    for (int i = tid; i < 1024; i += 256) {
      int k = i >> 6, n = i & 63;
      Bs[k][n] = W[(long)(k0 + k) * N + n0 + n];
    }
    __syncthreads();
    for (int k = 0; k < 16; ++k) {
      float a[4], bq[4];
      for (int ii = 0; ii < 4; ++ii) a[ii]  = As[k][ty * 4 + ii];
      for (int jj = 0; jj < 4; ++jj) bq[jj] = Bs[k][tx * 4 + jj];
      for (int ii = 0; ii < 4; ++ii)
        for (int jj = 0; jj < 4; ++jj) acc[ii][jj] += a[ii] * bq[jj];
    }
  }
  for (int jj = 0; jj < 4; ++jj) {
    int n = n0 + tx * 4 + jj;
    float bv = bias[n];
    float cs = 0.f, cq = 0.f;
    for (int ii = 0; ii < 4; ++ii) {
      float val = acc[ii][jj] + bv;
      C[(long)(m0 + ty * 4 + ii) * N + n] = val;
      cs += val; cq += val * val;
    }
    colS[ty][tx * 4 + jj] = cs;
    colQ[ty][tx * 4 + jj] = cq;
    __syncthreads();   // note: inside jj loop -> 4 rounds of reduce
    if (tid < 64) {
      float s = 0.f, ss = 0.f;
      for (int t = 0; t < 16; ++t) { s += colS[t][tid]; ss += colQ[t][tid]; }
      if ((tid & 3) == jj) {   // only the matching quarter writes this round
      }
    }
    __syncthreads();
  }
  // simpler, correct reduction: redo with all 64 cols staged at once
  for (int jj = 0; jj < 4; ++jj) {
    int n = n0 + tx * 4 + jj;
    float bv = bias[n];
    float cs = 0.f, cq = 0.f;
    for (int ii = 0; ii < 4; ++ii) {
      float val = acc[ii][jj] + bv;
      cs += val; cq += val * val;
    }
    colS[ty][tx * 4 + jj] = cs;
    colQ[ty][tx * 4 + jj] = cq;
    __syncthreads();
    if (tid < 64) {
      float s = 0.f, ss = 0.f;
      for (int t = 0; t < 16; ++t) { s += colS[t][tid]; ss += colQ[t][tid]; }
      if (tid >= jj * 16 && tid < jj * 16 + 16) { /* dummy keep */ }
      psumC[blockIdx.x * N + n0 + tid] = s;
      psqC [blockIdx.x * N + n0 + tid] = ss;
    }
    __syncthreads();
    break;  // single pass actually covers all 64 cols (tx*4+jj spans via tx); see note
  }
}

// ---------------------------------------------------------------------------
// K6: out = leaky(bn2(y2)) @ W3[256,2] + b3.  grid 16 x 256.
// ---------------------------------------------------------------------------
__global__ __launch_bounds__(256) void final_out(
    const float* __restrict__ y2,
    const float* __restrict__ psum2, const float* __restrict__ psq2,
    const float* __restrict__ g, const float* __restrict__ bta,
    const float* __restrict__ w3, const float* __restrict__ b3,
    float* __restrict__ out) {
  __shared__ float sc2[256], sh2[256];
  __shared__ float p0[256], p1[256];
  int tid = threadIdx.x;
  {
    float s = 0.f, ss = 0.f;
    for (int rc = 0; rc < 16; ++rc) { s += psum2[rc * 256 + tid]; ss += psq2[rc * 256 + tid]; }
    float mu = s * (1.f / 1024.f), var = ss * (1.f / 1024.f) - mu * mu;
    float scv = rsqrtf(var + 1e-5f) * g[tid];
    sc2[tid] = scv; sh2[tid] = bta[tid] - mu * scv;
  }
  __syncthreads();
  int row = blockIdx.x * 64 + (tid >> 2), q = tid & 3;
  const float* yr = y2 + (long)row * 256;
  float a0 = 0.f, a1 = 0.f;
  for (int k = q * 64; k < q * 64 + 64; ++k) {
    float v = yr[k] * sc2[k] + sh2[k];
    v = v > 0.f ? v : 0.1f * v;
    a0 += v * w3[2 * k];
    a1 += v * w3[2 * k + 1];
  }
  p0[tid] = a0; p1[tid] = a1;
  __syncthreads();
  if (q == 0) {
    out[row * 2 + 0] = p0[tid] + p0[tid + 1] + p0[tid + 2] + p0[tid + 3] + b3[0];
    out[row * 2 + 1] = p1[tid] + p1[tid + 1] + p1[tid + 2] + p1[tid + 3] + b3[1];
  }
}

// ---------------------------------------------------------------------------

extern "C" void kernel_launch(void* const* d_in, const int* in_sizes, int n_in,
                              void* d_out, int out_size, void* d_ws, size_t ws_size,
                              hipStream_t stream) {
  const int* uid  = (const int*)d_in[0];
  const int* mid  = (const int*)d_in[1];
  const int* cat  = (const int*)d_in[2];
  const int* hmid = (const int*)d_in[3];
  const int* hcat = (const int*)d_in[4];
  const int* mask = (const int*)d_in[5];
  const float* user_table = (const float*)d_in[6];
  const float* mat_table  = (const float*)d_in[7];
  const float* cat_table  = (const float*)d_in[8];
  const float* lau_w1 = (const float*)d_in[9];
  const float* lau_b1 = (const float*)d_in[10];
  const float* lau_w2 = (const float*)d_in[11];
  const float* lau_b2 = (const float*)d_in[12];
  const float* lau_w3 = (const float*)d_in[13];
  const float* lau_b3 = (const float*)d_in[14];
  const float* bn0_g = (const float*)d_in[15];
  const float* bn0_b = (const float*)d_in[16];
  const float* mlp_w1 = (const float*)d_in[17];
  const float* mlp_b1 = (const float*)d_in[18];
  const float* bn1_g = (const float*)d_in[19];
  const float* bn1_b = (const float*)d_in[20];
  const float* mlp_w2 = (const float*)d_in[21];
  const float* mlp_b2 = (const float*)d_in[22];
  const float* bn2_g = (const float*)d_in[23];
  const float* bn2_b = (const float*)d_in[24];
  const float* mlp_w3 = (const float*)d_in[25];
  const float* mlp_b3 = (const float*)d_in[26];
  float* out = (float*)d_out;

  char* w = (char*)d_ws;
  size_t off = 0;
  auto take = [&](size_t bytes) { size_t o = off; off += (bytes + 255) & ~(size_t)255; return o; };
  u16*   Xh     = (u16*)  (w + take((size_t)MROWS * 128 * 2));
  float* AW     = (float*)(w + take((size_t)MROWS * 4));
  float* cur    = (float*)(w + take((size_t)BB * 128 * 4));
  float* bias1p = (float*)(w + take((size_t)BB * 256 * 4));
  float* xmlp   = (float*)(w + take((size_t)BB * 448 * 4));
  float* y1     = (float*)(w + take((size_t)BB * 512 * 4));
  float* y2     = (float*)(w + take((size_t)BB * 256 * 4));
  u16*   WpT    = (u16*)  (w + take(256 * 256 * 2));
  float* Wq     = (float*)(w + take(128 * 256 * 4));
  u16*   W2T    = (u16*)  (w + take(128 * 256 * 2));
  float* psum0  = (float*)(w + take(16 * 448 * 4));
  float* psq0   = (float*)(w + take(16 * 448 * 4));
  float* psum1  = (float*)(w + take(16 * 512 * 4));
  float* psq1   = (float*)(w + take(16 * 512 * 4));
  float* psum2  = (float*)(w + take(16 * 256 * 4));
  float* psq2   = (float*)(w + take(16 * 256 * 4));

  prep_weights<<<512, 256, 0, stream>>>(lau_w1, lau_w2, WpT, Wq, W2T);
  prep_batch<<<BB, 256, 0, stream>>>(mid, cat, mat_table, cat_table, lau_b1, Wq, cur, bias1p);
  lau_fused<<<MROWS / 64, 256, 0, stream>>>(hmid, hcat, mat_table, cat_table, cur, bias1p,
                                            WpT, W2T, lau_b2, lau_w3, lau_b3, Xh, AW);
  softmax_pool<<<BB, 256, 0, stream>>>(AW, mask, uid, user_table, cur, Xh, xmlp);
  {
    dim3 g(448 / 64, 16);
    colstats<<<g, 256, 0, stream>>>(xmlp, 448, psum0, psq0);
  }
  {
    dim3 g(16, 512 / 64);
    gemm_bn<false><<<g, 256, 0, stream>>>(xmlp, 448, psum0, psq0, bn0_g, bn0_b,
                                          mlp_w1, mlp_b1, 512, y1, psum1, psq1);
  }
  {
    dim3 g(16, 256 / 64);
    gemm_bn<true><<<g, 256, 0, stream>>>(y1, 512, psum1, psq1, bn1_g, bn1_b,
                                         mlp_w2, mlp_b2, 256, y2, psum2, psq2);
  }
  final_out<<<16, 256, 0, stream>>>(y2, psum2, psq2, bn2_g, bn2_b, mlp_w3, mlp_b3, out);
}

// Round 3
// 748.063 us; speedup vs baseline: 1.3609x; 1.0425x over previous
//
#include <hip/hip_runtime.h>

#define BB 1024
#define TT 200
#define MROWS (BB*TT)   // 204800

typedef unsigned short u16;
typedef __attribute__((ext_vector_type(8))) short bf16x8;
typedef __attribute__((ext_vector_type(4))) float f32x4;

__device__ __forceinline__ u16 f2bf(float f) {
  unsigned u = __float_as_uint(f);
  u += 0x7fff + ((u >> 16) & 1);
  return (u16)(u >> 16);
}
__device__ __forceinline__ float bf2f(u16 h) {
  return __uint_as_float(((unsigned)h) << 16);
}

// ---------------------------------------------------------------------------
// K0: fold + transpose LAU weights to bf16.
// comb = [cur, hist, cur-hist, cur*hist] @ W1  ==  cur@(Wa+Wc) + hist@(Wb-Wc) + (cur*hist)@Wd
// WpT[n][k] (256x256): k<128 -> W1[128+k][n]-W1[256+k][n] ; k>=128 -> W1[384+k-128][n]
// Wq [k][j] (128x256) fp32: W1[k][j]+W1[256+k][j]
// W2T[n][k] (128x256): W2[k][n]
// ---------------------------------------------------------------------------
__global__ void prep_weights(const float* __restrict__ w1, const float* __restrict__ w2,
                             u16* __restrict__ WpT, float* __restrict__ Wq,
                             u16* __restrict__ W2T) {
  int i = blockIdx.x * 256 + threadIdx.x;
  if (i < 65536) {
    int n = i >> 8, k = i & 255;
    float v;
    if (k < 128) v = w1[(128 + k) * 256 + n] - w1[(256 + k) * 256 + n];
    else         v = w1[(384 + (k - 128)) * 256 + n];
    WpT[n * 256 + k] = f2bf(v);
  } else if (i < 98304) {
    int j = i - 65536;
    int k = j >> 8, jc = j & 255;
    Wq[j] = w1[k * 256 + jc] + w1[(256 + k) * 256 + jc];
  } else if (i < 131072) {
    int j = i - 98304;           // j = n*256 + k
    int n = j >> 8, k = j & 255;
    W2T[j] = f2bf(w2[k * 128 + n]);
  }
}

// ---------------------------------------------------------------------------
// K1: per-batch cur gather + bias1p = lau_b1 + cur @ Wq  (fp32)
// ---------------------------------------------------------------------------
__global__ __launch_bounds__(256) void prep_batch(
    const int* __restrict__ mid, const int* __restrict__ cat,
    const float* __restrict__ mat_table, const float* __restrict__ cat_table,
    const float* __restrict__ lau_b1, const float* __restrict__ Wq,
    float* __restrict__ cur, float* __restrict__ bias1p) {
  int b = blockIdx.x, tid = threadIdx.x;
  __shared__ float curL[128];
  if (tid < 64)        curL[tid] = mat_table[(long)mid[b] * 64 + tid];
  else if (tid < 128)  curL[tid] = cat_table[(long)cat[b] * 64 + (tid - 64)];
  __syncthreads();
  if (tid < 128) cur[b * 128 + tid] = curL[tid];
  float s = lau_b1[tid];
  for (int k = 0; k < 128; ++k) s += curL[k] * Wq[k * 256 + tid];
  bias1p[b * 256 + tid] = s;
}

// ---------------------------------------------------------------------------
// K2 (fused): gather hist -> LDS comb -> gemm1 (B direct from L2-resident
// global, NO B staging) -> sigmoid(h1) in-place -> gemm2 -> sigmoid -> w3 dot.
// LDS = A tile only (~35 KB) -> 4 blocks/CU; 4 barriers per block total.
// ---------------------------------------------------------------------------
__global__ __launch_bounds__(256) void lau_fused(
    const int* __restrict__ hmid, const int* __restrict__ hcat,
    const float* __restrict__ mat_table, const float* __restrict__ cat_table,
    const float* __restrict__ cur, const float* __restrict__ bias1p,
    const u16* __restrict__ WpT, const u16* __restrict__ W2T,
    const float* __restrict__ b2, const float* __restrict__ w3,
    const float* __restrict__ b3,
    u16* __restrict__ Xh, float* __restrict__ AW) {
  __shared__ __align__(16) u16 Al[64 * 264];   // comb rows (later h1), +8 pad
  __shared__ float awp[4][64];
  int tid = threadIdx.x, wave = tid >> 6, l = tid & 63;
  int q = l >> 4, r16 = l & 15;
  long mBase = (long)blockIdx.x * 64;

  // gather: 64 rows x 128 fp32 (mat 0-63, cat 64-127); build [hist | cur*hist] bf16
  for (int i = tid; i < 2048; i += 256) {
    int r = i >> 5, c4 = i & 31;
    long bt = mBase + r;
    int b = (int)(bt / TT);
    int e0 = c4 * 4;
    float4 hv;
    if (e0 < 64) hv = *(const float4*)(mat_table + (long)hmid[bt] * 64 + e0);
    else         hv = *(const float4*)(cat_table + (long)hcat[bt] * 64 + (e0 - 64));
    float4 cv = *(const float4*)(cur + b * 128 + e0);
    u16 hb[4] = {f2bf(hv.x), f2bf(hv.y), f2bf(hv.z), f2bf(hv.w)};
    u16 pb[4] = {f2bf(hv.x * cv.x), f2bf(hv.y * cv.y), f2bf(hv.z * cv.z), f2bf(hv.w * cv.w)};
    *(ushort4*)(Al + r * 264 + e0)       = *(ushort4*)hb;
    *(ushort4*)(Al + r * 264 + 128 + e0) = *(ushort4*)pb;
    *(ushort4*)(Xh + bt * 128 + e0)      = *(ushort4*)hb;
  }
  __syncthreads();                             // barrier 1

  // ---- layer 1: h1 = sigmoid(comb @ Wp + bias1p), B fragments from global ----
  f32x4 acc1[4][4] = {};
  const u16* wp1 = WpT + ((long)(wave * 64 + r16)) * 256 + q * 8;
  #pragma unroll
  for (int ki = 0; ki < 8; ++ki) {
    bf16x8 a[4];
    #pragma unroll
    for (int mt = 0; mt < 4; ++mt)
      a[mt] = *(const bf16x8*)(Al + (mt * 16 + r16) * 264 + ki * 32 + q * 8);
    #pragma unroll
    for (int nt = 0; nt < 4; ++nt) {
      bf16x8 bq = *(const bf16x8*)(wp1 + nt * (16 * 256) + ki * 32);
      #pragma unroll
      for (int mt = 0; mt < 4; ++mt)
        acc1[mt][nt] = __builtin_amdgcn_mfma_f32_16x16x32_bf16(a[mt], bq, acc1[mt][nt], 0, 0, 0);
    }
  }
  __syncthreads();                             // barrier 2 (Al reads done)
  #pragma unroll
  for (int mt = 0; mt < 4; ++mt)
    #pragma unroll
    for (int r = 0; r < 4; ++r) {
      int row = mt * 16 + q * 4 + r;
      int bidx = (int)((mBase + row) / TT);
      const float* bp = bias1p + (long)bidx * 256;
      #pragma unroll
      for (int nt = 0; nt < 4; ++nt) {
        int col = wave * 64 + nt * 16 + r16;
        float z = acc1[mt][nt][r] + bp[col];
        Al[row * 264 + col] = f2bf(1.f / (1.f + __expf(-z)));
      }
    }
  __syncthreads();                             // barrier 3 (h1 visible)

  // ---- layer 2: h2 = sigmoid(h1 @ W2 + b2); aw = h2 @ w3 + b3 ----
  f32x4 acc2[4][2] = {};
  const u16* wp2 = W2T + ((long)(wave * 32 + r16)) * 256 + q * 8;
  #pragma unroll
  for (int ki = 0; ki < 8; ++ki) {
    bf16x8 a[4];
    #pragma unroll
    for (int mt = 0; mt < 4; ++mt)
      a[mt] = *(const bf16x8*)(Al + (mt * 16 + r16) * 264 + ki * 32 + q * 8);
    #pragma unroll
    for (int nt = 0; nt < 2; ++nt) {
      bf16x8 bq = *(const bf16x8*)(wp2 + nt * (16 * 256) + ki * 32);
      #pragma unroll
      for (int mt = 0; mt < 4; ++mt)
        acc2[mt][nt] = __builtin_amdgcn_mfma_f32_16x16x32_bf16(a[mt], bq, acc2[mt][nt], 0, 0, 0);
    }
  }
  float rp[4][4];
  #pragma unroll
  for (int mt = 0; mt < 4; ++mt)
    #pragma unroll
    for (int r = 0; r < 4; ++r) rp[mt][r] = 0.f;
  #pragma unroll
  for (int nt = 0; nt < 2; ++nt) {
    int col = wave * 32 + nt * 16 + r16;
    float b2v = b2[col], w3v = w3[col];
    #pragma unroll
    for (int mt = 0; mt < 4; ++mt)
      #pragma unroll
      for (int r = 0; r < 4; ++r) {
        float z = acc2[mt][nt][r] + b2v;
        rp[mt][r] += w3v / (1.f + __expf(-z));
      }
  }
  #pragma unroll
  for (int off = 1; off < 16; off <<= 1)
    #pragma unroll
    for (int mt = 0; mt < 4; ++mt)
      #pragma unroll
      for (int r = 0; r < 4; ++r)
        rp[mt][r] += __shfl_xor(rp[mt][r], off, 16);
  if (r16 == 0)
    #pragma unroll
    for (int mt = 0; mt < 4; ++mt)
      #pragma unroll
      for (int r = 0; r < 4; ++r)
        awp[wave][mt * 16 + q * 4 + r] = rp[mt][r];
  __syncthreads();                             // barrier 4
  if (tid < 64)
    AW[mBase + tid] = awp[0][tid] + awp[1][tid] + awp[2][tid] + awp[3][tid] + b3[0];
}

// ---------------------------------------------------------------------------
// K3: per-b masked softmax over T, weighted pools from Xh, assemble x[B,448]
// ---------------------------------------------------------------------------
__global__ __launch_bounds__(256) void softmax_pool(
    const float* __restrict__ AW, const int* __restrict__ mask,
    const int* __restrict__ uid, const float* __restrict__ user_table,
    const float* __restrict__ cur, const u16* __restrict__ Xh,
    float* __restrict__ Xmlp) {
  int b = blockIdx.x, tid = threadIdx.x;
  __shared__ float red[256];
  __shared__ float sc[TT], mkf[TT];
  __shared__ float ps[512];
  int mk = 0;
  float masked = -3.0e38f;
  if (tid < TT) {
    mk = mask[b * TT + tid];
    masked = mk ? AW[b * TT + tid] : -2147483648.0f;
  }
  red[tid] = masked; __syncthreads();
  for (int s = 128; s > 0; s >>= 1) { if (tid < s) red[tid] = fmaxf(red[tid], red[tid + s]); __syncthreads(); }
  float mx = red[0]; __syncthreads();
  float ev = (tid < TT) ? __expf(masked - mx) : 0.f;
  red[tid] = ev; __syncthreads();
  for (int s = 128; s > 0; s >>= 1) { if (tid < s) red[tid] += red[tid + s]; __syncthreads(); }
  float denom = red[0]; __syncthreads();
  red[tid] = (tid < TT) ? (float)mk : 0.f; __syncthreads();
  for (int s = 128; s > 0; s >>= 1) { if (tid < s) red[tid] += red[tid + s]; __syncthreads(); }
  float cnt = red[0]; __syncthreads();
  if (tid < TT) { sc[tid] = (ev / denom) * (float)mk; mkf[tid] = (float)mk; }
  __syncthreads();
  int c = tid & 127, p = tid >> 7;
  const u16* xb = Xh + (long)b * TT * 128 + c;
  float sL = 0.f, sH = 0.f;
  for (int t = p; t < TT; t += 2) {
    float hv = bf2f(xb[(long)t * 128]);
    sL += sc[t] * hv;
    sH += mkf[t] * hv;
  }
  ps[tid] = sL; ps[256 + tid] = sH;
  __syncthreads();
  if (tid < 128) {
    float lau  = ps[tid] + ps[tid + 128];
    float hsum = ps[256 + tid] + ps[256 + tid + 128];
    Xmlp[b * 448 + 192 + tid] = lau;
    Xmlp[b * 448 + 320 + tid] = hsum / cnt;
  } else {
    int j = tid - 128;
    Xmlp[b * 448 + 64 + j] = cur[b * 128 + j];
    if (j < 64) Xmlp[b * 448 + j] = user_table[(long)uid[b] * 64 + j];
  }
}

// ---------------------------------------------------------------------------
// K4: column partial sums/sumsq of X[1024, cols] into [16][cols] chunks
// grid: (cols/64, 16)
// ---------------------------------------------------------------------------
__global__ __launch_bounds__(256) void colstats(const float* __restrict__ X, int cols,
                                                float* __restrict__ psum,
                                                float* __restrict__ psq) {
  int cg = blockIdx.x, rc = blockIdx.y;
  int c = threadIdx.x & 63, ty = threadIdx.x >> 6;
  int col = cg * 64 + c;
  float s = 0.f, ss = 0.f;
  for (int i = 0; i < 16; ++i) {
    int r = rc * 64 + ty + i * 4;
    float v = X[(long)r * cols + col];
    s += v; ss += v * v;
  }
  __shared__ float s1[256], s2[256];
  s1[threadIdx.x] = s; s2[threadIdx.x] = ss;
  __syncthreads();
  if (ty == 0) {
    s  = s1[c] + s1[c + 64] + s1[c + 128] + s1[c + 192];
    ss = s2[c] + s2[c + 64] + s2[c + 128] + s2[c + 192];
    psum[rc * cols + col] = s;
    psq [rc * cols + col] = ss;
  }
}

// ---------------------------------------------------------------------------
// K5: C[1024,N] = (act(bn(A)) @ W) + bias, and per-M-tile column stats of C.
// bn scale/shift reconstructed from partials in LDS. 64x64 tiles, BK=16.
// ---------------------------------------------------------------------------
template <bool LEAKY>
__global__ __launch_bounds__(256) void gemm_bn(
    const float* __restrict__ A, int K,
    const float* __restrict__ psumA, const float* __restrict__ psqA,
    const float* __restrict__ g, const float* __restrict__ bta,
    const float* __restrict__ W, const float* __restrict__ bias, int N,
    float* __restrict__ C, float* __restrict__ psumC, float* __restrict__ psqC) {
  __shared__ float As[16][65], Bs[16][65];
  __shared__ float scK[512], shK[512];
  __shared__ float colS[16][64], colQ[16][64];
  int tid = threadIdx.x;
  for (int j = tid; j < K; j += 256) {
    float s = 0.f, ss = 0.f;
    for (int rc = 0; rc < 16; ++rc) { s += psumA[rc * K + j]; ss += psqA[rc * K + j]; }
    float mu = s * (1.f / 1024.f), var = ss * (1.f / 1024.f) - mu * mu;
    float scv = rsqrtf(var + 1e-5f) * g[j];
    scK[j] = scv; shK[j] = bta[j] - mu * scv;
  }
  __syncthreads();
  int m0 = blockIdx.x * 64, n0 = blockIdx.y * 64;
  int tx = tid & 15, ty = tid >> 4;
  float acc[4][4] = {};
  for (int k0 = 0; k0 < K; k0 += 16) {
    __syncthreads();
    for (int i = tid; i < 1024; i += 256) {
      int m = i >> 4, k = i & 15;
      float v = A[(long)(m0 + m) * K + k0 + k] * scK[k0 + k] + shK[k0 + k];
      if (LEAKY) v = v > 0.f ? v : 0.1f * v;
      As[k][m] = v;
    }
    for (int i = tid; i < 1024; i += 256) {
      int k = i >> 6, n = i & 63;
      Bs[k][n] = W[(long)(k0 + k) * N + n0 + n];
    }
    __syncthreads();
    for (int k = 0; k < 16; ++k) {
      float a[4], bq[4];
      for (int ii = 0; ii < 4; ++ii) a[ii]  = As[k][ty * 4 + ii];
      for (int jj = 0; jj < 4; ++jj) bq[jj] = Bs[k][tx * 4 + jj];
      for (int ii = 0; ii < 4; ++ii)
        for (int jj = 0; jj < 4; ++jj) acc[ii][jj] += a[ii] * bq[jj];
    }
  }
  // write C and stage per-thread column partials (all 64 cols covered: tx*4+jj)
  float cs4[4], cq4[4];
  for (int jj = 0; jj < 4; ++jj) {
    int n = n0 + tx * 4 + jj;
    float bv = bias[n];
    float cs = 0.f, cq = 0.f;
    for (int ii = 0; ii < 4; ++ii) {
      float val = acc[ii][jj] + bv;
      C[(long)(m0 + ty * 4 + ii) * N + n] = val;
      cs += val; cq += val * val;
    }
    cs4[jj] = cs; cq4[jj] = cq;
  }
  __syncthreads();
  for (int jj = 0; jj < 4; ++jj) {
    colS[ty][tx * 4 + jj] = cs4[jj];
    colQ[ty][tx * 4 + jj] = cq4[jj];
  }
  __syncthreads();
  if (tid < 64) {
    float s = 0.f, ss = 0.f;
    for (int t = 0; t < 16; ++t) { s += colS[t][tid]; ss += colQ[t][tid]; }
    psumC[blockIdx.x * N + n0 + tid] = s;
    psqC [blockIdx.x * N + n0 + tid] = ss;
  }
}

// ---------------------------------------------------------------------------
// K6: out = leaky(bn2(y2)) @ W3[256,2] + b3.  grid 16 x 256.
// ---------------------------------------------------------------------------
__global__ __launch_bounds__(256) void final_out(
    const float* __restrict__ y2,
    const float* __restrict__ psum2, const float* __restrict__ psq2,
    const float* __restrict__ g, const float* __restrict__ bta,
    const float* __restrict__ w3, const float* __restrict__ b3,
    float* __restrict__ out) {
  __shared__ float sc2[256], sh2[256];
  __shared__ float p0[256], p1[256];
  int tid = threadIdx.x;
  {
    float s = 0.f, ss = 0.f;
    for (int rc = 0; rc < 16; ++rc) { s += psum2[rc * 256 + tid]; ss += psq2[rc * 256 + tid]; }
    float mu = s * (1.f / 1024.f), var = ss * (1.f / 1024.f) - mu * mu;
    float scv = rsqrtf(var + 1e-5f) * g[tid];
    sc2[tid] = scv; sh2[tid] = bta[tid] - mu * scv;
  }
  __syncthreads();
  int row = blockIdx.x * 64 + (tid >> 2), q = tid & 3;
  const float* yr = y2 + (long)row * 256;
  float a0 = 0.f, a1 = 0.f;
  for (int k = q * 64; k < q * 64 + 64; ++k) {
    float v = yr[k] * sc2[k] + sh2[k];
    v = v > 0.f ? v : 0.1f * v;
    a0 += v * w3[2 * k];
    a1 += v * w3[2 * k + 1];
  }
  p0[tid] = a0; p1[tid] = a1;
  __syncthreads();
  if (q == 0) {
    out[row * 2 + 0] = p0[tid] + p0[tid + 1] + p0[tid + 2] + p0[tid + 3] + b3[0];
    out[row * 2 + 1] = p1[tid] + p1[tid + 1] + p1[tid + 2] + p1[tid + 3] + b3[1];
  }
}

// ---------------------------------------------------------------------------

extern "C" void kernel_launch(void* const* d_in, const int* in_sizes, int n_in,
                              void* d_out, int out_size, void* d_ws, size_t ws_size,
                              hipStream_t stream) {
  const int* uid  = (const int*)d_in[0];
  const int* mid  = (const int*)d_in[1];
  const int* cat  = (const int*)d_in[2];
  const int* hmid = (const int*)d_in[3];
  const int* hcat = (const int*)d_in[4];
  const int* mask = (const int*)d_in[5];
  const float* user_table = (const float*)d_in[6];
  const float* mat_table  = (const float*)d_in[7];
  const float* cat_table  = (const float*)d_in[8];
  const float* lau_w1 = (const float*)d_in[9];
  const float* lau_b1 = (const float*)d_in[10];
  const float* lau_w2 = (const float*)d_in[11];
  const float* lau_b2 = (const float*)d_in[12];
  const float* lau_w3 = (const float*)d_in[13];
  const float* lau_b3 = (const float*)d_in[14];
  const float* bn0_g = (const float*)d_in[15];
  const float* bn0_b = (const float*)d_in[16];
  const float* mlp_w1 = (const float*)d_in[17];
  const float* mlp_b1 = (const float*)d_in[18];
  const float* bn1_g = (const float*)d_in[19];
  const float* bn1_b = (const float*)d_in[20];
  const float* mlp_w2 = (const float*)d_in[21];
  const float* mlp_b2 = (const float*)d_in[22];
  const float* bn2_g = (const float*)d_in[23];
  const float* bn2_b = (const float*)d_in[24];
  const float* mlp_w3 = (const float*)d_in[25];
  const float* mlp_b3 = (const float*)d_in[26];
  float* out = (float*)d_out;

  char* w = (char*)d_ws;
  size_t off = 0;
  auto take = [&](size_t bytes) { size_t o = off; off += (bytes + 255) & ~(size_t)255; return o; };
  u16*   Xh     = (u16*)  (w + take((size_t)MROWS * 128 * 2));
  float* AW     = (float*)(w + take((size_t)MROWS * 4));
  float* cur    = (float*)(w + take((size_t)BB * 128 * 4));
  float* bias1p = (float*)(w + take((size_t)BB * 256 * 4));
  float* xmlp   = (float*)(w + take((size_t)BB * 448 * 4));
  float* y1     = (float*)(w + take((size_t)BB * 512 * 4));
  float* y2     = (float*)(w + take((size_t)BB * 256 * 4));
  u16*   WpT    = (u16*)  (w + take(256 * 256 * 2));
  float* Wq     = (float*)(w + take(128 * 256 * 4));
  u16*   W2T    = (u16*)  (w + take(128 * 256 * 2));
  float* psum0  = (float*)(w + take(16 * 448 * 4));
  float* psq0   = (float*)(w + take(16 * 448 * 4));
  float* psum1  = (float*)(w + take(16 * 512 * 4));
  float* psq1   = (float*)(w + take(16 * 512 * 4));
  float* psum2  = (float*)(w + take(16 * 256 * 4));
  float* psq2   = (float*)(w + take(16 * 256 * 4));

  prep_weights<<<512, 256, 0, stream>>>(lau_w1, lau_w2, WpT, Wq, W2T);
  prep_batch<<<BB, 256, 0, stream>>>(mid, cat, mat_table, cat_table, lau_b1, Wq, cur, bias1p);
  lau_fused<<<MROWS / 64, 256, 0, stream>>>(hmid, hcat, mat_table, cat_table, cur, bias1p,
                                            WpT, W2T, lau_b2, lau_w3, lau_b3, Xh, AW);
  softmax_pool<<<BB, 256, 0, stream>>>(AW, mask, uid, user_table, cur, Xh, xmlp);
  {
    dim3 g(448 / 64, 16);
    colstats<<<g, 256, 0, stream>>>(xmlp, 448, psum0, psq0);
  }
  {
    dim3 g(16, 512 / 64);
    gemm_bn<false><<<g, 256, 0, stream>>>(xmlp, 448, psum0, psq0, bn0_g, bn0_b,
                                          mlp_w1, mlp_b1, 512, y1, psum1, psq1);
  }
  {
    dim3 g(16, 256 / 64);
    gemm_bn<true><<<g, 256, 0, stream>>>(y1, 512, psum1, psq1, bn1_g, bn1_b,
                                         mlp_w2, mlp_b2, 256, y2, psum2, psq2);
  }
  final_out<<<16, 256, 0, stream>>>(y2, psum2, psq2, bn2_g, bn2_b, mlp_w3, mlp_b3, out);
}

// Round 4
// 709.386 us; speedup vs baseline: 1.4351x; 1.0545x over previous
//
#include <hip/hip_runtime.h>

#define BB 1024
#define TT 200
#define MROWS (BB*TT)   // 204800

typedef unsigned short u16;
typedef __attribute__((ext_vector_type(8))) short bf16x8;
typedef __attribute__((ext_vector_type(4))) float f32x4;

__device__ __forceinline__ u16 f2bf(float f) {
  unsigned u = __float_as_uint(f);
  u += 0x7fff + ((u >> 16) & 1);
  return (u16)(u >> 16);
}
__device__ __forceinline__ float bf2f(u16 h) {
  return __uint_as_float(((unsigned)h) << 16);
}
__device__ __forceinline__ float fast_sigmoid(float z) {
  return __builtin_amdgcn_rcpf(1.f + __expf(-z));
}

// ---------------------------------------------------------------------------
// K0: fold + transpose LAU weights to bf16.
// comb = [cur, hist, cur-hist, cur*hist] @ W1  ==  cur@(Wa+Wc) + hist@(Wb-Wc) + (cur*hist)@Wd
// WpT[n][k] (256x256): k<128 -> W1[128+k][n]-W1[256+k][n] ; k>=128 -> W1[384+k-128][n]
// Wq [k][j] (128x256) fp32: W1[k][j]+W1[256+k][j]
// W2T[n][k] (128x256): W2[k][n]
// ---------------------------------------------------------------------------
__global__ void prep_weights(const float* __restrict__ w1, const float* __restrict__ w2,
                             u16* __restrict__ WpT, float* __restrict__ Wq,
                             u16* __restrict__ W2T) {
  int i = blockIdx.x * 256 + threadIdx.x;
  if (i < 65536) {
    int n = i >> 8, k = i & 255;
    float v;
    if (k < 128) v = w1[(128 + k) * 256 + n] - w1[(256 + k) * 256 + n];
    else         v = w1[(384 + (k - 128)) * 256 + n];
    WpT[n * 256 + k] = f2bf(v);
  } else if (i < 98304) {
    int j = i - 65536;
    int k = j >> 8, jc = j & 255;
    Wq[j] = w1[k * 256 + jc] + w1[(256 + k) * 256 + jc];
  } else if (i < 131072) {
    int j = i - 98304;           // j = n*256 + k
    int n = j >> 8, k = j & 255;
    W2T[j] = f2bf(w2[k * 128 + n]);
  }
}

// ---------------------------------------------------------------------------
// K1: per-batch cur gather + bias1p = lau_b1 + cur @ Wq  (fp32)
// ---------------------------------------------------------------------------
__global__ __launch_bounds__(256) void prep_batch(
    const int* __restrict__ mid, const int* __restrict__ cat,
    const float* __restrict__ mat_table, const float* __restrict__ cat_table,
    const float* __restrict__ lau_b1, const float* __restrict__ Wq,
    float* __restrict__ cur, float* __restrict__ bias1p) {
  int b = blockIdx.x, tid = threadIdx.x;
  __shared__ float curL[128];
  if (tid < 64)        curL[tid] = mat_table[(long)mid[b] * 64 + tid];
  else if (tid < 128)  curL[tid] = cat_table[(long)cat[b] * 64 + (tid - 64)];
  __syncthreads();
  if (tid < 128) cur[b * 128 + tid] = curL[tid];
  float s = lau_b1[tid];
  for (int k = 0; k < 128; ++k) s += curL[k] * Wq[k * 256 + tid];
  bias1p[b * 256 + tid] = s;
}

// ---------------------------------------------------------------------------
// K2 (fused): gather hist -> LDS comb -> gemm1 (B rotated through registers,
// loads issued ~16 MFMAs before their use) -> sigmoid(h1) in-place -> gemm2 ->
// sigmoid -> w3 dot.  Per-thread bias values prefetched into registers at
// kernel entry (block spans <=2 batch rows).  4 barriers per block.
// ---------------------------------------------------------------------------
__global__ __launch_bounds__(256, 4) void lau_fused(
    const int* __restrict__ hmid, const int* __restrict__ hcat,
    const float* __restrict__ mat_table, const float* __restrict__ cat_table,
    const float* __restrict__ cur, const float* __restrict__ bias1p,
    const u16* __restrict__ WpT, const u16* __restrict__ W2T,
    const float* __restrict__ b2, const float* __restrict__ w3,
    const float* __restrict__ b3,
    u16* __restrict__ Xh, float* __restrict__ AW) {
  __shared__ __align__(16) u16 Al[64 * 264];   // comb rows (later h1), +8 pad
  __shared__ float awp[4][64];
  int tid = threadIdx.x, wave = tid >> 6, l = tid & 63;
  int q = l >> 4, r16 = l & 15;
  long mBase = (long)blockIdx.x * 64;
  int b0 = (int)(mBase / TT), b1 = (int)((mBase + 63) / TT);
  long thresh = (long)(b0 + 1) * TT;

  // prefetch per-thread epilogue constants (fully hidden behind gather+gemm1)
  float bias_a[4], bias_b[4];
  #pragma unroll
  for (int nt = 0; nt < 4; ++nt) {
    int col = wave * 64 + nt * 16 + r16;
    bias_a[nt] = bias1p[(long)b0 * 256 + col];
    bias_b[nt] = bias1p[(long)b1 * 256 + col];
  }
  float b2v[2], w3v[2];
  #pragma unroll
  for (int nt = 0; nt < 2; ++nt) {
    int col = wave * 32 + nt * 16 + r16;
    b2v[nt] = b2[col]; w3v[nt] = w3[col];
  }
  float b3v = b3[0];

  // gather: 64 rows x 128 fp32 (mat 0-63, cat 64-127); build [hist | cur*hist]
  for (int i = tid; i < 2048; i += 256) {
    int r = i >> 5, c4 = i & 31;
    long bt = mBase + r;
    int b = (int)(bt / TT);
    int e0 = c4 * 4;
    float4 hv;
    if (e0 < 64) hv = *(const float4*)(mat_table + (long)hmid[bt] * 64 + e0);
    else         hv = *(const float4*)(cat_table + (long)hcat[bt] * 64 + (e0 - 64));
    float4 cv = *(const float4*)(cur + b * 128 + e0);
    u16 hb[4] = {f2bf(hv.x), f2bf(hv.y), f2bf(hv.z), f2bf(hv.w)};
    u16 pb[4] = {f2bf(hv.x * cv.x), f2bf(hv.y * cv.y), f2bf(hv.z * cv.z), f2bf(hv.w * cv.w)};
    *(ushort4*)(Al + r * 264 + e0)       = *(ushort4*)hb;
    *(ushort4*)(Al + r * 264 + 128 + e0) = *(ushort4*)pb;
    *(ushort4*)(Xh + bt * 128 + e0)      = *(ushort4*)hb;
  }
  __syncthreads();                             // barrier 1

  // ---- layer 1: h1 = sigmoid(comb @ Wp + bias1p) ----
  const u16* wp1 = WpT + ((long)(wave * 64 + r16)) * 256 + q * 8;
  bf16x8 bfr[4];
  #pragma unroll
  for (int nt = 0; nt < 4; ++nt)
    bfr[nt] = *(const bf16x8*)(wp1 + nt * 4096);
  f32x4 acc1[4][4] = {};
  #pragma unroll
  for (int ki = 0; ki < 8; ++ki) {
    bf16x8 a[4];
    #pragma unroll
    for (int mt = 0; mt < 4; ++mt)
      a[mt] = *(const bf16x8*)(Al + (mt * 16 + r16) * 264 + ki * 32 + q * 8);
    #pragma unroll
    for (int nt = 0; nt < 4; ++nt) {
      bf16x8 bu = bfr[nt];
      if (ki < 7)            // rotate: reload this frag for ki+1 (compile-time)
        bfr[nt] = *(const bf16x8*)(wp1 + nt * 4096 + (ki + 1) * 32);
      #pragma unroll
      for (int mt = 0; mt < 4; ++mt)
        acc1[mt][nt] = __builtin_amdgcn_mfma_f32_16x16x32_bf16(a[mt], bu, acc1[mt][nt], 0, 0, 0);
    }
  }
  __syncthreads();                             // barrier 2 (Al reads done)
  #pragma unroll
  for (int mt = 0; mt < 4; ++mt)
    #pragma unroll
    for (int r = 0; r < 4; ++r) {
      int row = mt * 16 + q * 4 + r;
      bool hi = (mBase + row) >= thresh;
      #pragma unroll
      for (int nt = 0; nt < 4; ++nt) {
        int col = wave * 64 + nt * 16 + r16;
        float z = acc1[mt][nt][r] + (hi ? bias_b[nt] : bias_a[nt]);
        Al[row * 264 + col] = f2bf(fast_sigmoid(z));
      }
    }
  __syncthreads();                             // barrier 3 (h1 visible)

  // ---- layer 2: h2 = sigmoid(h1 @ W2 + b2); aw = h2 @ w3 + b3 ----
  const u16* wp2 = W2T + ((long)(wave * 32 + r16)) * 256 + q * 8;
  bf16x8 b2f[2];
  b2f[0] = *(const bf16x8*)(wp2);
  b2f[1] = *(const bf16x8*)(wp2 + 4096);
  f32x4 acc2[4][2] = {};
  #pragma unroll
  for (int ki = 0; ki < 8; ++ki) {
    bf16x8 a[4];
    #pragma unroll
    for (int mt = 0; mt < 4; ++mt)
      a[mt] = *(const bf16x8*)(Al + (mt * 16 + r16) * 264 + ki * 32 + q * 8);
    #pragma unroll
    for (int nt = 0; nt < 2; ++nt) {
      bf16x8 bu = b2f[nt];
      if (ki < 7)
        b2f[nt] = *(const bf16x8*)(wp2 + nt * 4096 + (ki + 1) * 32);
      #pragma unroll
      for (int mt = 0; mt < 4; ++mt)
        acc2[mt][nt] = __builtin_amdgcn_mfma_f32_16x16x32_bf16(a[mt], bu, acc2[mt][nt], 0, 0, 0);
    }
  }
  float rp[4][4];
  #pragma unroll
  for (int mt = 0; mt < 4; ++mt)
    #pragma unroll
    for (int r = 0; r < 4; ++r) rp[mt][r] = 0.f;
  #pragma unroll
  for (int nt = 0; nt < 2; ++nt) {
    #pragma unroll
    for (int mt = 0; mt < 4; ++mt)
      #pragma unroll
      for (int r = 0; r < 4; ++r) {
        float z = acc2[mt][nt][r] + b2v[nt];
        rp[mt][r] += w3v[nt] * fast_sigmoid(z);
      }
  }
  #pragma unroll
  for (int off = 1; off < 16; off <<= 1)
    #pragma unroll
    for (int mt = 0; mt < 4; ++mt)
      #pragma unroll
      for (int r = 0; r < 4; ++r)
        rp[mt][r] += __shfl_xor(rp[mt][r], off, 16);
  if (r16 == 0)
    #pragma unroll
    for (int mt = 0; mt < 4; ++mt)
      #pragma unroll
      for (int r = 0; r < 4; ++r)
        awp[wave][mt * 16 + q * 4 + r] = rp[mt][r];
  __syncthreads();                             // barrier 4
  if (tid < 64)
    AW[mBase + tid] = awp[0][tid] + awp[1][tid] + awp[2][tid] + awp[3][tid] + b3v;
}

// ---------------------------------------------------------------------------
// K3: per-b masked softmax over T, weighted pools from Xh, assemble x[B,448]
// pooling: coalesced u32 (bf16x2) loads, 4-way t-parallel per column pair
// ---------------------------------------------------------------------------
__global__ __launch_bounds__(256) void softmax_pool(
    const float* __restrict__ AW, const int* __restrict__ mask,
    const int* __restrict__ uid, const float* __restrict__ user_table,
    const float* __restrict__ cur, const u16* __restrict__ Xh,
    float* __restrict__ Xmlp) {
  int b = blockIdx.x, tid = threadIdx.x;
  __shared__ float redA[256], redB[256];
  __shared__ float sc[TT], mkf[TT];
  __shared__ float pl0[256], pl1[256], ph0[256], ph1[256];
  int mk = 0;
  float masked = -3.0e38f;
  if (tid < TT) {
    mk = mask[b * TT + tid];
    masked = mk ? AW[b * TT + tid] : -2147483648.0f;
  }
  redA[tid] = masked; __syncthreads();
  for (int s = 128; s > 0; s >>= 1) { if (tid < s) redA[tid] = fmaxf(redA[tid], redA[tid + s]); __syncthreads(); }
  float mx = redA[0]; __syncthreads();
  float ev = (tid < TT) ? __expf(masked - mx) : 0.f;
  redA[tid] = ev; redB[tid] = (tid < TT) ? (float)mk : 0.f;
  __syncthreads();
  for (int s = 128; s > 0; s >>= 1) {
    if (tid < s) { redA[tid] += redA[tid + s]; redB[tid] += redB[tid + s]; }
    __syncthreads();
  }
  float rdenom = __builtin_amdgcn_rcpf(redA[0]);
  float cnt = redB[0]; __syncthreads();
  if (tid < TT) { sc[tid] = ev * rdenom * (float)mk; mkf[tid] = (float)mk; }
  __syncthreads();
  int cp = tid & 63, p = tid >> 6;   // column pair 2cp,2cp+1 ; t-phase p
  const u16* xb = Xh + (long)b * TT * 128 + 2 * cp;
  float sL0 = 0.f, sL1 = 0.f, sH0 = 0.f, sH1 = 0.f;
  for (int t = p; t < TT; t += 4) {
    unsigned v = *(const unsigned*)(xb + (long)t * 128);
    float h0 = bf2f((u16)(v & 0xffff));
    float h1 = bf2f((u16)(v >> 16));
    float s = sc[t], m = mkf[t];
    sL0 += s * h0; sL1 += s * h1;
    sH0 += m * h0; sH1 += m * h1;
  }
  pl0[tid] = sL0; pl1[tid] = sL1; ph0[tid] = sH0; ph1[tid] = sH1;
  __syncthreads();
  if (tid < 128) {
    int c2 = tid >> 1, part = tid & 1;
    const float* PL = part ? pl1 : pl0;
    const float* PH = part ? ph1 : ph0;
    float lau = PL[c2] + PL[64 + c2] + PL[128 + c2] + PL[192 + c2];
    float hs  = PH[c2] + PH[64 + c2] + PH[128 + c2] + PH[192 + c2];
    Xmlp[b * 448 + 192 + tid] = lau;
    Xmlp[b * 448 + 320 + tid] = hs * __builtin_amdgcn_rcpf(cnt);
  } else {
    int j = tid - 128;
    Xmlp[b * 448 + 64 + j] = cur[b * 128 + j];
    if (j < 64) Xmlp[b * 448 + j] = user_table[(long)uid[b] * 64 + j];
  }
}

// ---------------------------------------------------------------------------
// K4: column partial sums/sumsq of X[1024, cols] into [16][cols] chunks
// grid: (cols/64, 16)
// ---------------------------------------------------------------------------
__global__ __launch_bounds__(256) void colstats(const float* __restrict__ X, int cols,
                                                float* __restrict__ psum,
                                                float* __restrict__ psq) {
  int cg = blockIdx.x, rc = blockIdx.y;
  int c = threadIdx.x & 63, ty = threadIdx.x >> 6;
  int col = cg * 64 + c;
  float s = 0.f, ss = 0.f;
  for (int i = 0; i < 16; ++i) {
    int r = rc * 64 + ty + i * 4;
    float v = X[(long)r * cols + col];
    s += v; ss += v * v;
  }
  __shared__ float s1[256], s2[256];
  s1[threadIdx.x] = s; s2[threadIdx.x] = ss;
  __syncthreads();
  if (ty == 0) {
    s  = s1[c] + s1[c + 64] + s1[c + 128] + s1[c + 192];
    ss = s2[c] + s2[c + 64] + s2[c + 128] + s2[c + 192];
    psum[rc * cols + col] = s;
    psq [rc * cols + col] = ss;
  }
}

// ---------------------------------------------------------------------------
// K5: C[1024,N] = (act(bn(A)) @ W) + bias, and per-M-tile column stats of C.
// bn scale/shift reconstructed from partials in LDS. 64x64 tiles, BK=16.
// ---------------------------------------------------------------------------
template <bool LEAKY>
__global__ __launch_bounds__(256) void gemm_bn(
    const float* __restrict__ A, int K,
    const float* __restrict__ psumA, const float* __restrict__ psqA,
    const float* __restrict__ g, const float* __restrict__ bta,
    const float* __restrict__ W, const float* __restrict__ bias, int N,
    float* __restrict__ C, float* __restrict__ psumC, float* __restrict__ psqC) {
  __shared__ float As[16][65], Bs[16][65];
  __shared__ float scK[512], shK[512];
  __shared__ float colS[16][64], colQ[16][64];
  int tid = threadIdx.x;
  for (int j = tid; j < K; j += 256) {
    float s = 0.f, ss = 0.f;
    for (int rc = 0; rc < 16; ++rc) { s += psumA[rc * K + j]; ss += psqA[rc * K + j]; }
    float mu = s * (1.f / 1024.f), var = ss * (1.f / 1024.f) - mu * mu;
    float scv = rsqrtf(var + 1e-5f) * g[j];
    scK[j] = scv; shK[j] = bta[j] - mu * scv;
  }
  __syncthreads();
  int m0 = blockIdx.x * 64, n0 = blockIdx.y * 64;
  int tx = tid & 15, ty = tid >> 4;
  float acc[4][4] = {};
  for (int k0 = 0; k0 < K; k0 += 16) {
    __syncthreads();
    for (int i = tid; i < 1024; i += 256) {
      int m = i >> 4, k = i & 15;
      float v = A[(long)(m0 + m) * K + k0 + k] * scK[k0 + k] + shK[k0 + k];
      if (LEAKY) v = v > 0.f ? v : 0.1f * v;
      As[k][m] = v;
    }
    for (int i = tid; i < 1024; i += 256) {
      int k = i >> 6, n = i & 63;
      Bs[k][n] = W[(long)(k0 + k) * N + n0 + n];
    }
    __syncthreads();
    for (int k = 0; k < 16; ++k) {
      float a[4], bq[4];
      for (int ii = 0; ii < 4; ++ii) a[ii]  = As[k][ty * 4 + ii];
      for (int jj = 0; jj < 4; ++jj) bq[jj] = Bs[k][tx * 4 + jj];
      for (int ii = 0; ii < 4; ++ii)
        for (int jj = 0; jj < 4; ++jj) acc[ii][jj] += a[ii] * bq[jj];
    }
  }
  // write C and stage per-thread column partials (all 64 cols covered: tx*4+jj)
  float cs4[4], cq4[4];
  for (int jj = 0; jj < 4; ++jj) {
    int n = n0 + tx * 4 + jj;
    float bv = bias[n];
    float cs = 0.f, cq = 0.f;
    for (int ii = 0; ii < 4; ++ii) {
      float val = acc[ii][jj] + bv;
      C[(long)(m0 + ty * 4 + ii) * N + n] = val;
      cs += val; cq += val * val;
    }
    cs4[jj] = cs; cq4[jj] = cq;
  }
  __syncthreads();
  for (int jj = 0; jj < 4; ++jj) {
    colS[ty][tx * 4 + jj] = cs4[jj];
    colQ[ty][tx * 4 + jj] = cq4[jj];
  }
  __syncthreads();
  if (tid < 64) {
    float s = 0.f, ss = 0.f;
    for (int t = 0; t < 16; ++t) { s += colS[t][tid]; ss += colQ[t][tid]; }
    psumC[blockIdx.x * N + n0 + tid] = s;
    psqC [blockIdx.x * N + n0 + tid] = ss;
  }
}

// ---------------------------------------------------------------------------
// K6: out = leaky(bn2(y2)) @ W3[256,2] + b3.  grid 16 x 256.
// ---------------------------------------------------------------------------
__global__ __launch_bounds__(256) void final_out(
    const float* __restrict__ y2,
    const float* __restrict__ psum2, const float* __restrict__ psq2,
    const float* __restrict__ g, const float* __restrict__ bta,
    const float* __restrict__ w3, const float* __restrict__ b3,
    float* __restrict__ out) {
  __shared__ float sc2[256], sh2[256];
  __shared__ float p0[256], p1[256];
  int tid = threadIdx.x;
  {
    float s = 0.f, ss = 0.f;
    for (int rc = 0; rc < 16; ++rc) { s += psum2[rc * 256 + tid]; ss += psq2[rc * 256 + tid]; }
    float mu = s * (1.f / 1024.f), var = ss * (1.f / 1024.f) - mu * mu;
    float scv = rsqrtf(var + 1e-5f) * g[tid];
    sc2[tid] = scv; sh2[tid] = bta[tid] - mu * scv;
  }
  __syncthreads();
  int row = blockIdx.x * 64 + (tid >> 2), q = tid & 3;
  const float* yr = y2 + (long)row * 256;
  float a0 = 0.f, a1 = 0.f;
  for (int k = q * 64; k < q * 64 + 64; ++k) {
    float v = yr[k] * sc2[k] + sh2[k];
    v = v > 0.f ? v : 0.1f * v;
    a0 += v * w3[2 * k];
    a1 += v * w3[2 * k + 1];
  }
  p0[tid] = a0; p1[tid] = a1;
  __syncthreads();
  if (q == 0) {
    out[row * 2 + 0] = p0[tid] + p0[tid + 1] + p0[tid + 2] + p0[tid + 3] + b3[0];
    out[row * 2 + 1] = p1[tid] + p1[tid + 1] + p1[tid + 2] + p1[tid + 3] + b3[1];
  }
}

// ---------------------------------------------------------------------------

extern "C" void kernel_launch(void* const* d_in, const int* in_sizes, int n_in,
                              void* d_out, int out_size, void* d_ws, size_t ws_size,
                              hipStream_t stream) {
  const int* uid  = (const int*)d_in[0];
  const int* mid  = (const int*)d_in[1];
  const int* cat  = (const int*)d_in[2];
  const int* hmid = (const int*)d_in[3];
  const int* hcat = (const int*)d_in[4];
  const int* mask = (const int*)d_in[5];
  const float* user_table = (const float*)d_in[6];
  const float* mat_table  = (const float*)d_in[7];
  const float* cat_table  = (const float*)d_in[8];
  const float* lau_w1 = (const float*)d_in[9];
  const float* lau_b1 = (const float*)d_in[10];
  const float* lau_w2 = (const float*)d_in[11];
  const float* lau_b2 = (const float*)d_in[12];
  const float* lau_w3 = (const float*)d_in[13];
  const float* lau_b3 = (const float*)d_in[14];
  const float* bn0_g = (const float*)d_in[15];
  const float* bn0_b = (const float*)d_in[16];
  const float* mlp_w1 = (const float*)d_in[17];
  const float* mlp_b1 = (const float*)d_in[18];
  const float* bn1_g = (const float*)d_in[19];
  const float* bn1_b = (const float*)d_in[20];
  const float* mlp_w2 = (const float*)d_in[21];
  const float* mlp_b2 = (const float*)d_in[22];
  const float* bn2_g = (const float*)d_in[23];
  const float* bn2_b = (const float*)d_in[24];
  const float* mlp_w3 = (const float*)d_in[25];
  const float* mlp_b3 = (const float*)d_in[26];
  float* out = (float*)d_out;

  char* w = (char*)d_ws;
  size_t off = 0;
  auto take = [&](size_t bytes) { size_t o = off; off += (bytes + 255) & ~(size_t)255; return o; };
  u16*   Xh     = (u16*)  (w + take((size_t)MROWS * 128 * 2));
  float* AW     = (float*)(w + take((size_t)MROWS * 4));
  float* cur    = (float*)(w + take((size_t)BB * 128 * 4));
  float* bias1p = (float*)(w + take((size_t)BB * 256 * 4));
  float* xmlp   = (float*)(w + take((size_t)BB * 448 * 4));
  float* y1     = (float*)(w + take((size_t)BB * 512 * 4));
  float* y2     = (float*)(w + take((size_t)BB * 256 * 4));
  u16*   WpT    = (u16*)  (w + take(256 * 256 * 2));
  float* Wq     = (float*)(w + take(128 * 256 * 4));
  u16*   W2T    = (u16*)  (w + take(128 * 256 * 2));
  float* psum0  = (float*)(w + take(16 * 448 * 4));
  float* psq0   = (float*)(w + take(16 * 448 * 4));
  float* psum1  = (float*)(w + take(16 * 512 * 4));
  float* psq1   = (float*)(w + take(16 * 512 * 4));
  float* psum2  = (float*)(w + take(16 * 256 * 4));
  float* psq2   = (float*)(w + take(16 * 256 * 4));

  prep_weights<<<512, 256, 0, stream>>>(lau_w1, lau_w2, WpT, Wq, W2T);
  prep_batch<<<BB, 256, 0, stream>>>(mid, cat, mat_table, cat_table, lau_b1, Wq, cur, bias1p);
  lau_fused<<<MROWS / 64, 256, 0, stream>>>(hmid, hcat, mat_table, cat_table, cur, bias1p,
                                            WpT, W2T, lau_b2, lau_w3, lau_b3, Xh, AW);
  softmax_pool<<<BB, 256, 0, stream>>>(AW, mask, uid, user_table, cur, Xh, xmlp);
  {
    dim3 g(448 / 64, 16);
    colstats<<<g, 256, 0, stream>>>(xmlp, 448, psum0, psq0);
  }
  {
    dim3 g(16, 512 / 64);
    gemm_bn<false><<<g, 256, 0, stream>>>(xmlp, 448, psum0, psq0, bn0_g, bn0_b,
                                          mlp_w1, mlp_b1, 512, y1, psum1, psq1);
  }
  {
    dim3 g(16, 256 / 64);
    gemm_bn<true><<<g, 256, 0, stream>>>(y1, 512, psum1, psq1, bn1_g, bn1_b,
                                         mlp_w2, mlp_b2, 256, y2, psum2, psq2);
  }
  final_out<<<16, 256, 0, stream>>>(y2, psum2, psq2, bn2_g, bn2_b, mlp_w3, mlp_b3, out);
}